// Round 1
// baseline (313.876 us; speedup 1.0000x reference)
//
#include <hip/hip_runtime.h>

// VQ argmin: 1-pass f16 SCREEN on matrix cores (xh.ch only, score error
// sigma ~9e-3) + exact fp32 parallel rescan for tokens whose screen
// best2-best1 gap < MARGIN (expected ~1.5% of tokens).
// This round: (1) cn folded into MFMA accumulator init (argmax of raw acc,
// deletes 64 fmaf/tile), (2) v_med3_f32 second-best tracking (4 VALU ops per
// candidate instead of 6), (3) barrier-free wave-private double-buffered
// staging with counted s_waitcnt vmcnt(4) (T3/T4) -- LDS B-buffers are
// per-wave, so the old 2-barriers-per-slice-pair (128 barrier drains) were
// pure overhead.

#define M_TOK  32768
#define DIM    128
#define KCODES 8192
#define BM     64
#define NT     (KCODES / 256)   // 32 n-tiles per block
#define MARGIN 0.10f            // ~8 sigma of screen pair error; gap scale 6.9

typedef _Float16 half8v __attribute__((ext_vector_type(8)));
typedef float float4v __attribute__((ext_vector_type(4)));

union H2U { _Float16 h; unsigned short u; };
__device__ __forceinline__ unsigned short f2h_bits(_Float16 h) {
  H2U c; c.h = h; return c.u;
}

__device__ __forceinline__ void gload_lds16(const void* g, void* l) {
  __builtin_amdgcn_global_load_lds(
      (const __attribute__((address_space(1))) unsigned int*)g,
      (__attribute__((address_space(3))) unsigned int*)l, 16, 0, 0);
}

#define WAIT_VMCNT4 asm volatile("s_waitcnt vmcnt(4)" ::: "memory")
#define WAIT_VMCNT0 asm volatile("s_waitcnt vmcnt(0)" ::: "memory")
#define WAIT_LGKM0  asm volatile("s_waitcnt lgkmcnt(0)" ::: "memory")

// ws layout: Cs f16[K][128] (hi only) | cnorm f32[K] | qcnt | qtok | kmin
#define CNORM_OFF  (KCODES * 256)
#define QCNT_OFF   (CNORM_OFF + KCODES * 4)
#define QTOK_OFF   (QCNT_OFF + 64)
#define KMIN_OFF   (QTOK_OFF + M_TOK * 4)

// -------------------------------------------------------------------------
// prep: exact fp32 cnorm + f16-hi codebook rows. Zeroes qcnt.
__global__ __launch_bounds__(256) void prep_kernel(
    const float* __restrict__ cb, unsigned short* __restrict__ Cs,
    float* __restrict__ cnorm, int* __restrict__ qcnt) {
  if (blockIdx.x == 0 && threadIdx.x == 0) *qcnt = 0;
  const int k = blockIdx.x * 4 + (threadIdx.x >> 6);
  const int lane = threadIdx.x & 63;
  const float2 v = ((const float2*)(cb + (size_t)k * DIM))[lane];
  float s = v.x * v.x + v.y * v.y;
  #pragma unroll
  for (int off = 32; off > 0; off >>= 1) s += __shfl_down(s, off);
  if (lane == 0) cnorm[k] = s;
  ushort2 hi;
  hi.x = f2h_bits((_Float16)v.x);
  hi.y = f2h_bits((_Float16)v.y);
  *(ushort2*)(Cs + (size_t)k * 128 + lane * 2) = hi;
}

// -------------------------------------------------------------------------
__global__ __launch_bounds__(256, 2) void vq_mfma_kernel(
    const float* __restrict__ ze, const unsigned short* __restrict__ Cs,
    const float* __restrict__ cnorm, const float* __restrict__ cb,
    int* __restrict__ qcnt, int* __restrict__ qtok,
    unsigned long long* __restrict__ kmin,
    float* __restrict__ out_zq, float* __restrict__ out_idx) {
  __shared__ char lds[49152];
  char* const As = lds;            // 16 KB: 64 rows x 256 B, seg-XOR swizzled
  char* const Bs = lds + 16384;    // 32 KB: 4 waves x 8 KB (2 slice bufs)

  const int tid = threadIdx.x;
  const int wn = tid >> 6;
  const int lane = tid & 63;
  const int quad = lane >> 4;
  const int l15 = lane & 15;
  const int m0 = blockIdx.x * BM;

  // Per-lane B-staging source offsets (R2/R4-verified mapping, hi-only rows:
  // 256 B stride). Dest slot s of local row r holds source seg s^((r>>1)&3).
  int loffC[4];
  #pragma unroll
  for (int c = 0; c < 4; ++c) {
    const int r = c * 16 + (lane >> 2);
    const int s = lane & 3;
    const int seg = s ^ ((r >> 1) & 3);
    loffC[c] = (wn * 64 + r) * 256 + seg * 16;
  }
  int boff[4];
  #pragma unroll
  for (int j = 0; j < 4; ++j) {
    const int n = j * 16 + l15;
    boff[j] = n * 64 + ((quad ^ ((n >> 1) & 3)) << 4);
  }
  char* const BsW = Bs + wn * 8192;

  // cnorm for tile 0 (prefetched; later tiles prefetched inside the loop).
  float cnv[4];
  #pragma unroll
  for (int j = 0; j < 4; ++j) cnv[j] = cnorm[wn * 64 + j * 16 + l15];

  // ---- stage As (hi only): fp32 -> f16, seg = (c>>3) ^ (r&7), 256 B rows --
  {
    const int r = tid >> 2;
    const int qh = tid & 3;
    const float* zrow = ze + (size_t)(m0 + r) * DIM + qh * 32;
    char* arow = As + r * 256;
    const int rx = r & 7;
    #pragma unroll
    for (int i = 0; i < 8; ++i) {
      const float4 v = *(const float4*)(zrow + i * 4);
      ushort4 hh;
      hh.x = f2h_bits((_Float16)v.x);
      hh.y = f2h_bits((_Float16)v.y);
      hh.z = f2h_bits((_Float16)v.z);
      hh.w = f2h_bits((_Float16)v.w);
      const int c = qh * 32 + i * 4;
      *(ushort4*)(arow + ((((c >> 3) ^ rx) << 4) | ((c & 7) << 1))) = hh;
    }
  }
  __syncthreads();

  // Prologue: stage slices 0,1 into the two wave-private B buffers.
  // (Wave-private LDS region -> no barrier needed, only vmcnt discipline.)
  #pragma unroll
  for (int p = 0; p < 2; ++p)
    #pragma unroll
    for (int c = 0; c < 4; ++c)
      gload_lds16((const char*)Cs + p * 64 + loffC[c],
                  BsW + p * 4096 + c * 1024);

  // Preload all A-hi fragments into registers (reused for all 32 n-tiles).
  half8v ahi[4][4];
  #pragma unroll
  for (int ks = 0; ks < 4; ++ks)
    #pragma unroll
    for (int i = 0; i < 4; ++i) {
      const int m = i * 16 + l15;
      const int kslot = ks * 4 + quad;
      ahi[ks][i] = *(const half8v*)(As + m * 256 + ((kslot ^ (m & 7)) << 4));
    }

  // Argmax of acc = -cn/2 + x.c  (equivalent to argmin of cn - 2 x.c).
  float bestv[16], secv[16], idxv[16];
  #pragma unroll
  for (int s = 0; s < 16; ++s) {
    bestv[s] = -3.4e38f; secv[s] = -3.4e38f; idxv[s] = 0.f;
  }

  for (int nt = 0; nt < NT; ++nt) {
    // acc init carries the -cn/2 bias (free: replaces the zero-init).
    float4v acc[4][4];
    #pragma unroll
    for (int j = 0; j < 4; ++j) {
      const float b = -0.5f * cnv[j];
      #pragma unroll
      for (int i = 0; i < 4; ++i) {
        acc[i][j][0] = b; acc[i][j][1] = b;
        acc[i][j][2] = b; acc[i][j][3] = b;
      }
    }
    // Prefetch next tile's cnorm during this tile's compute.
    float cnvn[4];
    if (nt + 1 < NT) {
      #pragma unroll
      for (int j = 0; j < 4; ++j)
        cnvn[j] = cnorm[(nt + 1) * 256 + wn * 64 + j * 16 + l15];
    }

    #pragma unroll
    for (int kk = 0; kk < 4; ++kk) {
      // g = nt*4 + kk; slice g+1 staged while slice g computes.
      const bool more = (kk < 3) || (nt + 1 < NT);
      if (more && (kk > 0 || nt > 0)) {
        WAIT_LGKM0;  // wave's ds_reads of the buffer being overwritten done
        const int ntn = (kk == 3) ? nt + 1 : nt;
        const int kkn = (kk + 1) & 3;
        const char* src = (const char*)Cs + (size_t)ntn * 65536 + kkn * 64;
        char* dst = BsW + ((kk + 1) & 1) * 4096;
        #pragma unroll
        for (int c = 0; c < 4; ++c)
          gload_lds16(src + loffC[c], dst + c * 1024);
      }
      if (more) { WAIT_VMCNT4; } else { WAIT_VMCNT0; }

      half8v bf[4];
      #pragma unroll
      for (int j = 0; j < 4; ++j)
        bf[j] = *(const half8v*)(BsW + (kk & 1) * 4096 + boff[j]);
      #pragma unroll
      for (int i = 0; i < 4; ++i)
        #pragma unroll
        for (int j = 0; j < 4; ++j)
          acc[i][j] = __builtin_amdgcn_mfma_f32_16x16x32_f16(
              ahi[kk][i], bf[j], acc[i][j], 0, 0, 0);
    }

    // Fold screen scores (argmax). Ascending n, strict > keeps lowest index
    // on ties. sec' = med3(sc, best, sec) is exactly the new runner-up.
    #pragma unroll
    for (int j = 0; j < 4; ++j) {
      const float nidx = (float)(nt * 256 + wn * 64 + j * 16 + l15);
      #pragma unroll
      for (int i = 0; i < 4; ++i)
        #pragma unroll
        for (int rg = 0; rg < 4; ++rg) {
          const float sc = acc[i][j][rg];
          const int slot = i * 4 + rg;
          const bool bt = sc > bestv[slot];
          secv[slot] = __builtin_amdgcn_fmed3f(sc, bestv[slot], secv[slot]);
          idxv[slot] = bt ? nidx : idxv[slot];
          bestv[slot] = fmaxf(bestv[slot], sc);
        }
    }
    if (nt + 1 < NT) {
      #pragma unroll
      for (int j = 0; j < 4; ++j) cnv[j] = cnvn[j];
    }
  }

  // Cross-lane reduce (16 lanes per token row, tie -> lowest index).
  #pragma unroll
  for (int slot = 0; slot < 16; ++slot) {
    float b = bestv[slot], sec = secv[slot], ix = idxv[slot];
    #pragma unroll
    for (int mk = 1; mk <= 8; mk <<= 1) {
      const float ob = __shfl_xor(b, mk);
      const float os = __shfl_xor(sec, mk);
      const float oi = __shfl_xor(ix, mk);
      const bool take = (ob > b) || (ob == b && oi < ix);
      const float loser = take ? b : ob;
      b = take ? ob : b;
      ix = take ? oi : ix;
      sec = fmaxf(fmaxf(sec, os), loser);
    }
    bestv[slot] = b; secv[slot] = sec; idxv[slot] = ix;
  }

  // Cross-wave merge via LDS (reuse As region after barrier).
  __syncthreads();
  float* const redB = (float*)lds;
  float* const redS = redB + 256;
  float* const redI = redB + 512;
  float* const lidxs = redB + 768;
  if (l15 == 0) {
    #pragma unroll
    for (int slot = 0; slot < 16; ++slot) {
      const int row = (slot >> 2) * 16 + quad * 4 + (slot & 3);
      redB[wn * 64 + row] = bestv[slot];
      redS[wn * 64 + row] = secv[slot];
      redI[wn * 64 + row] = idxv[slot];
    }
  }
  __syncthreads();
  if (tid < 64) {
    float b = redB[tid], sec = redS[tid], ix = redI[tid];
    #pragma unroll
    for (int w = 1; w < 4; ++w) {
      const float ob = redB[w * 64 + tid];
      const float os = redS[w * 64 + tid];
      const float oi = redI[w * 64 + tid];
      const bool take = (ob > b) || (ob == b && oi < ix);
      const float loser = take ? b : ob;
      b = take ? ob : b;
      ix = take ? oi : ix;
      sec = fmaxf(fmaxf(sec, os), loser);
    }
    out_idx[m0 + tid] = ix;
    lidxs[tid] = ix;
    // acc-domain gap: sc = -2*acc  =>  sc-gap = 2*(b - sec).
    if (b - sec < 0.5f * MARGIN) {  // ambiguous under screen error -> rescan
      kmin[m0 + tid] = ~0ull;
      const int p = atomicAdd(qcnt, 1);
      qtok[p] = m0 + tid;
    }
  }
  __syncthreads();

  // Provisional z_q gather for this block's 64 tokens.
  const int tl = tid >> 2, qp = tid & 3;
  const int code = (int)lidxs[tl];
  const float4* src = (const float4*)(cb + (size_t)code * DIM);
  float4* dst = (float4*)(out_zq + (size_t)(m0 + tl) * DIM);
  #pragma unroll
  for (int p = 0; p < 8; ++p) dst[qp + p * 4] = src[qp + p * 4];
}

// -------------------------------------------------------------------------
// Parallel exact rescan: block b handles (token slot b>>5, code chunk b&31).
// Each of 256 threads scores ONE code, block-tree argmin, atomicMin merge
// on packed (score,idx) key (monotone map: lower score -> smaller key).
__global__ __launch_bounds__(256) void rescan_part_kernel(
    const float* __restrict__ ze, const float* __restrict__ cb,
    const float* __restrict__ cnorm, const int* __restrict__ qcnt,
    const int* __restrict__ qtok, unsigned long long* __restrict__ kmin) {
  __shared__ float xsh[DIM];
  __shared__ float rs[256];
  __shared__ int ri[256];
  const int tid = threadIdx.x;
  const int chunk = blockIdx.x & 31;
  const int n = *qcnt;
  for (int qi = blockIdx.x >> 5; qi < n; qi += (gridDim.x >> 5)) {
    const int token = qtok[qi];
    __syncthreads();
    if (tid < 32)
      ((float4*)xsh)[tid] = ((const float4*)(ze + (size_t)token * DIM))[tid];
    __syncthreads();
    const int code = chunk * 256 + tid;
    const float* crow = cb + (size_t)code * DIM;
    float dot = 0.f;
    #pragma unroll
    for (int d = 0; d < DIM; ++d) dot = fmaf(xsh[d], crow[d], dot);
    rs[tid] = fmaf(-2.f, dot, cnorm[code]);
    ri[tid] = code;
    __syncthreads();
    #pragma unroll
    for (int off = 128; off > 0; off >>= 1) {
      if (tid < off) {
        const float so = rs[tid + off];
        const int io = ri[tid + off];
        if (so < rs[tid] || (so == rs[tid] && io < ri[tid])) {
          rs[tid] = so; ri[tid] = io;
        }
      }
      __syncthreads();
    }
    if (tid == 0) {
      union { float f; unsigned int u; } c; c.f = rs[0];
      const unsigned int m = (c.u >> 31) ? ~c.u : (c.u | 0x80000000u);
      const unsigned long long key =
          ((unsigned long long)m << 32) | (unsigned int)ri[0];
      atomicMin(&kmin[token], key);
    }
    __syncthreads();
  }
}

// -------------------------------------------------------------------------
// Apply rescan results: decode keys, rewrite idx + z_q rows.
__global__ __launch_bounds__(256) void rescan_apply_kernel(
    const float* __restrict__ cb, const int* __restrict__ qcnt,
    const int* __restrict__ qtok, const unsigned long long* __restrict__ kmin,
    float* __restrict__ out_zq, float* __restrict__ out_idx) {
  const int tid = threadIdx.x;
  const int n = *qcnt;
  for (int qi = blockIdx.x; qi < n; qi += gridDim.x) {
    const int token = qtok[qi];
    const int code = (int)(unsigned int)(kmin[token] & 0xFFFFFFFFull);
    if (tid == 0) out_idx[token] = (float)code;
    if (tid < 32)
      ((float4*)(out_zq + (size_t)token * DIM))[tid] =
          ((const float4*)(cb + (size_t)code * DIM))[tid];
  }
}

// -------------------------------------------------------------------------
extern "C" void kernel_launch(void* const* d_in, const int* in_sizes, int n_in,
                              void* d_out, int out_size, void* d_ws,
                              size_t ws_size, hipStream_t stream) {
  const float* ze = (const float*)d_in[0];
  const float* cb = (const float*)d_in[1];
  float* out = (float*)d_out;

  unsigned short* Cs = (unsigned short*)d_ws;
  float* cnorm = (float*)((char*)d_ws + CNORM_OFF);
  int* qcnt = (int*)((char*)d_ws + QCNT_OFF);
  int* qtok = (int*)((char*)d_ws + QTOK_OFF);
  unsigned long long* kmin = (unsigned long long*)((char*)d_ws + KMIN_OFF);

  prep_kernel<<<KCODES / 4, 256, 0, stream>>>(cb, Cs, cnorm, qcnt);
  vq_mfma_kernel<<<M_TOK / BM, 256, 0, stream>>>(
      ze, Cs, cnorm, cb, qcnt, qtok, kmin, out, out + (size_t)M_TOK * DIM);
  rescan_part_kernel<<<4096, 256, 0, stream>>>(ze, cb, cnorm, qcnt, qtok,
                                               kmin);
  rescan_apply_kernel<<<256, 256, 0, stream>>>(cb, qcnt, qtok, kmin, out,
                                               out + (size_t)M_TOK * DIM);
}

// Round 2
// 281.098 us; speedup vs baseline: 1.1166x; 1.1166x over previous
//
#include <hip/hip_runtime.h>

// VQ argmin: 1-pass f16 SCREEN on matrix cores (xh.ch only, score error
// sigma ~9e-3) + exact fp32 parallel rescan for tokens whose screen
// best2-best1 gap < MARGIN (expected ~1.5% of tokens).
// R2: revert R1's barrier-free pipeline (regressed: +4 VGPR -> scratch spill,
// WRITE_SIZE 16.5->28.3 MB). Keep R0's harness-verified 2-barrier staging
// structure; keep only R1's verified fold improvements: cn folded into MFMA
// accumulator init (argmax of raw acc, deletes 64 fmaf/tile) and v_med3_f32
// second-best tracking (4 VALU ops/candidate instead of 6).

#define M_TOK  32768
#define DIM    128
#define KCODES 8192
#define BM     64
#define NT     (KCODES / 256)   // 32 n-tiles per block
#define MARGIN 0.10f            // ~8 sigma of screen pair error; gap scale 6.9

typedef _Float16 half8v __attribute__((ext_vector_type(8)));
typedef float float4v __attribute__((ext_vector_type(4)));

union H2U { _Float16 h; unsigned short u; };
__device__ __forceinline__ unsigned short f2h_bits(_Float16 h) {
  H2U c; c.h = h; return c.u;
}

__device__ __forceinline__ void gload_lds16(const void* g, void* l) {
  __builtin_amdgcn_global_load_lds(
      (const __attribute__((address_space(1))) unsigned int*)g,
      (__attribute__((address_space(3))) unsigned int*)l, 16, 0, 0);
}

// ws layout: Cs f16[K][128] (hi only) | cnorm f32[K] | qcnt | qtok | kmin
#define CNORM_OFF  (KCODES * 256)
#define QCNT_OFF   (CNORM_OFF + KCODES * 4)
#define QTOK_OFF   (QCNT_OFF + 64)
#define KMIN_OFF   (QTOK_OFF + M_TOK * 4)

// -------------------------------------------------------------------------
// prep: exact fp32 cnorm + f16-hi codebook rows. Zeroes qcnt.
__global__ __launch_bounds__(256) void prep_kernel(
    const float* __restrict__ cb, unsigned short* __restrict__ Cs,
    float* __restrict__ cnorm, int* __restrict__ qcnt) {
  if (blockIdx.x == 0 && threadIdx.x == 0) *qcnt = 0;
  const int k = blockIdx.x * 4 + (threadIdx.x >> 6);
  const int lane = threadIdx.x & 63;
  const float2 v = ((const float2*)(cb + (size_t)k * DIM))[lane];
  float s = v.x * v.x + v.y * v.y;
  #pragma unroll
  for (int off = 32; off > 0; off >>= 1) s += __shfl_down(s, off);
  if (lane == 0) cnorm[k] = s;
  ushort2 hi;
  hi.x = f2h_bits((_Float16)v.x);
  hi.y = f2h_bits((_Float16)v.y);
  *(ushort2*)(Cs + (size_t)k * 128 + lane * 2) = hi;
}

// -------------------------------------------------------------------------
__global__ __launch_bounds__(256, 2) void vq_mfma_kernel(
    const float* __restrict__ ze, const unsigned short* __restrict__ Cs,
    const float* __restrict__ cnorm, const float* __restrict__ cb,
    int* __restrict__ qcnt, int* __restrict__ qtok,
    unsigned long long* __restrict__ kmin,
    float* __restrict__ out_zq, float* __restrict__ out_idx) {
  __shared__ char lds[49152];
  char* const As = lds;            // 16 KB: 64 rows x 256 B, seg-XOR swizzled
  char* const Bs = lds + 16384;    // 32 KB: 4 waves x 8 KB (2 slice bufs)

  const int tid = threadIdx.x;
  const int wn = tid >> 6;
  const int lane = tid & 63;
  const int quad = lane >> 4;
  const int l15 = lane & 15;
  const int m0 = blockIdx.x * BM;

  // Per-lane B-staging source offsets (R2/R4-verified mapping, hi-only rows:
  // 256 B stride). Dest slot s of local row r holds source seg s^((r>>1)&3).
  int loffC[4];
  #pragma unroll
  for (int c = 0; c < 4; ++c) {
    const int r = c * 16 + (lane >> 2);
    const int s = lane & 3;
    const int seg = s ^ ((r >> 1) & 3);
    loffC[c] = (wn * 64 + r) * 256 + seg * 16;
  }
  int boff[4];
  #pragma unroll
  for (int j = 0; j < 4; ++j) {
    const int n = j * 16 + l15;
    boff[j] = n * 64 + ((quad ^ ((n >> 1) & 3)) << 4);
  }
  char* const BsW = Bs + wn * 8192;

  // ---- stage As (hi only): fp32 -> f16, seg = (c>>3) ^ (r&7), 256 B rows --
  {
    const int r = tid >> 2;
    const int qh = tid & 3;
    const float* zrow = ze + (size_t)(m0 + r) * DIM + qh * 32;
    char* arow = As + r * 256;
    const int rx = r & 7;
    #pragma unroll
    for (int i = 0; i < 8; ++i) {
      const float4 v = *(const float4*)(zrow + i * 4);
      ushort4 hh;
      hh.x = f2h_bits((_Float16)v.x);
      hh.y = f2h_bits((_Float16)v.y);
      hh.z = f2h_bits((_Float16)v.z);
      hh.w = f2h_bits((_Float16)v.w);
      const int c = qh * 32 + i * 4;
      *(ushort4*)(arow + ((((c >> 3) ^ rx) << 4) | ((c & 7) << 1))) = hh;
    }
  }
  __syncthreads();

  // Preload all A-hi fragments into registers (reused for all 32 n-tiles).
  half8v ahi[4][4];
  #pragma unroll
  for (int ks = 0; ks < 4; ++ks)
    #pragma unroll
    for (int i = 0; i < 4; ++i) {
      const int m = i * 16 + l15;
      const int kslot = ks * 4 + quad;
      ahi[ks][i] = *(const half8v*)(As + m * 256 + ((kslot ^ (m & 7)) << 4));
    }

  // Argmax of acc = -cn/2 + x.c  (equivalent to argmin of cn - 2 x.c).
  float bestv[16], secv[16], idxv[16];
  #pragma unroll
  for (int s = 0; s < 16; ++s) {
    bestv[s] = -3.4e38f; secv[s] = -3.4e38f; idxv[s] = 0.f;
  }

  for (int nt = 0; nt < NT; ++nt) {
    const char* const tile = (const char*)Cs + (size_t)nt * 65536;
    float cnv[4];
    #pragma unroll
    for (int j = 0; j < 4; ++j)
      cnv[j] = cnorm[nt * 256 + wn * 64 + j * 16 + l15];

    // acc init carries the -cn/2 bias (free: replaces the zero-init).
    float4v acc[4][4];
    #pragma unroll
    for (int j = 0; j < 4; ++j) {
      const float b = -0.5f * cnv[j];
      #pragma unroll
      for (int i = 0; i < 4; ++i) {
        acc[i][j][0] = b; acc[i][j][1] = b;
        acc[i][j][2] = b; acc[i][j][3] = b;
      }
    }

    // 4 k-slices per tile, staged TWO per barrier pair (halves drain count).
    #pragma unroll
    for (int t = 0; t < 2; ++t) {
      __syncthreads();  // prior pair consumed before DMA overwrite
      #pragma unroll
      for (int p = 0; p < 2; ++p)
        #pragma unroll
        for (int c = 0; c < 4; ++c)
          gload_lds16(tile + (t * 2 + p) * 64 + loffC[c],
                      BsW + p * 4096 + c * 1024);
      __syncthreads();  // drains vmcnt -> both slices ready

      #pragma unroll
      for (int p = 0; p < 2; ++p) {
        const int kk = t * 2 + p;
        half8v bf[4];
        #pragma unroll
        for (int j = 0; j < 4; ++j)
          bf[j] = *(const half8v*)(BsW + p * 4096 + boff[j]);
        #pragma unroll
        for (int i = 0; i < 4; ++i)
          #pragma unroll
          for (int j = 0; j < 4; ++j)
            acc[i][j] = __builtin_amdgcn_mfma_f32_16x16x32_f16(
                ahi[kk][i], bf[j], acc[i][j], 0, 0, 0);
      }
    }

    // Fold screen scores (argmax). Ascending n, strict > keeps lowest index
    // on ties. sec' = med3(sc, best, sec) is exactly the new runner-up.
    #pragma unroll
    for (int j = 0; j < 4; ++j) {
      const float nidx = (float)(nt * 256 + wn * 64 + j * 16 + l15);
      #pragma unroll
      for (int i = 0; i < 4; ++i)
        #pragma unroll
        for (int rg = 0; rg < 4; ++rg) {
          const float sc = acc[i][j][rg];
          const int slot = i * 4 + rg;
          const bool bt = sc > bestv[slot];
          secv[slot] = __builtin_amdgcn_fmed3f(sc, bestv[slot], secv[slot]);
          idxv[slot] = bt ? nidx : idxv[slot];
          bestv[slot] = fmaxf(bestv[slot], sc);
        }
    }
  }

  // Cross-lane reduce (16 lanes per token row, tie -> lowest index).
  #pragma unroll
  for (int slot = 0; slot < 16; ++slot) {
    float b = bestv[slot], sec = secv[slot], ix = idxv[slot];
    #pragma unroll
    for (int mk = 1; mk <= 8; mk <<= 1) {
      const float ob = __shfl_xor(b, mk);
      const float os = __shfl_xor(sec, mk);
      const float oi = __shfl_xor(ix, mk);
      const bool take = (ob > b) || (ob == b && oi < ix);
      const float loser = take ? b : ob;
      b = take ? ob : b;
      ix = take ? oi : ix;
      sec = fmaxf(fmaxf(sec, os), loser);
    }
    bestv[slot] = b; secv[slot] = sec; idxv[slot] = ix;
  }

  // Cross-wave merge via LDS (reuse As region after barrier).
  __syncthreads();
  float* const redB = (float*)lds;
  float* const redS = redB + 256;
  float* const redI = redB + 512;
  float* const lidxs = redB + 768;
  if (l15 == 0) {
    #pragma unroll
    for (int slot = 0; slot < 16; ++slot) {
      const int row = (slot >> 2) * 16 + quad * 4 + (slot & 3);
      redB[wn * 64 + row] = bestv[slot];
      redS[wn * 64 + row] = secv[slot];
      redI[wn * 64 + row] = idxv[slot];
    }
  }
  __syncthreads();
  if (tid < 64) {
    float b = redB[tid], sec = redS[tid], ix = redI[tid];
    #pragma unroll
    for (int w = 1; w < 4; ++w) {
      const float ob = redB[w * 64 + tid];
      const float os = redS[w * 64 + tid];
      const float oi = redI[w * 64 + tid];
      const bool take = (ob > b) || (ob == b && oi < ix);
      const float loser = take ? b : ob;
      b = take ? ob : b;
      ix = take ? oi : ix;
      sec = fmaxf(fmaxf(sec, os), loser);
    }
    out_idx[m0 + tid] = ix;
    lidxs[tid] = ix;
    // acc-domain gap: sc = -2*acc  =>  sc-gap = 2*(b - sec).
    if (b - sec < 0.5f * MARGIN) {  // ambiguous under screen error -> rescan
      kmin[m0 + tid] = ~0ull;
      const int p = atomicAdd(qcnt, 1);
      qtok[p] = m0 + tid;
    }
  }
  __syncthreads();

  // Provisional z_q gather for this block's 64 tokens.
  const int tl = tid >> 2, qp = tid & 3;
  const int code = (int)lidxs[tl];
  const float4* src = (const float4*)(cb + (size_t)code * DIM);
  float4* dst = (float4*)(out_zq + (size_t)(m0 + tl) * DIM);
  #pragma unroll
  for (int p = 0; p < 8; ++p) dst[qp + p * 4] = src[qp + p * 4];
}

// -------------------------------------------------------------------------
// Parallel exact rescan: block b handles (token slot b>>5, code chunk b&31).
// Each of 256 threads scores ONE code, block-tree argmin, atomicMin merge
// on packed (score,idx) key (monotone map: lower score -> smaller key).
__global__ __launch_bounds__(256) void rescan_part_kernel(
    const float* __restrict__ ze, const float* __restrict__ cb,
    const float* __restrict__ cnorm, const int* __restrict__ qcnt,
    const int* __restrict__ qtok, unsigned long long* __restrict__ kmin) {
  __shared__ float xsh[DIM];
  __shared__ float rs[256];
  __shared__ int ri[256];
  const int tid = threadIdx.x;
  const int chunk = blockIdx.x & 31;
  const int n = *qcnt;
  for (int qi = blockIdx.x >> 5; qi < n; qi += (gridDim.x >> 5)) {
    const int token = qtok[qi];
    __syncthreads();
    if (tid < 32)
      ((float4*)xsh)[tid] = ((const float4*)(ze + (size_t)token * DIM))[tid];
    __syncthreads();
    const int code = chunk * 256 + tid;
    const float* crow = cb + (size_t)code * DIM;
    float dot = 0.f;
    #pragma unroll
    for (int d = 0; d < DIM; ++d) dot = fmaf(xsh[d], crow[d], dot);
    rs[tid] = fmaf(-2.f, dot, cnorm[code]);
    ri[tid] = code;
    __syncthreads();
    #pragma unroll
    for (int off = 128; off > 0; off >>= 1) {
      if (tid < off) {
        const float so = rs[tid + off];
        const int io = ri[tid + off];
        if (so < rs[tid] || (so == rs[tid] && io < ri[tid])) {
          rs[tid] = so; ri[tid] = io;
        }
      }
      __syncthreads();
    }
    if (tid == 0) {
      union { float f; unsigned int u; } c; c.f = rs[0];
      const unsigned int m = (c.u >> 31) ? ~c.u : (c.u | 0x80000000u);
      const unsigned long long key =
          ((unsigned long long)m << 32) | (unsigned int)ri[0];
      atomicMin(&kmin[token], key);
    }
    __syncthreads();
  }
}

// -------------------------------------------------------------------------
// Apply rescan results: decode keys, rewrite idx + z_q rows.
__global__ __launch_bounds__(256) void rescan_apply_kernel(
    const float* __restrict__ cb, const int* __restrict__ qcnt,
    const int* __restrict__ qtok, const unsigned long long* __restrict__ kmin,
    float* __restrict__ out_zq, float* __restrict__ out_idx) {
  const int tid = threadIdx.x;
  const int n = *qcnt;
  for (int qi = blockIdx.x; qi < n; qi += gridDim.x) {
    const int token = qtok[qi];
    const int code = (int)(unsigned int)(kmin[token] & 0xFFFFFFFFull);
    if (tid == 0) out_idx[token] = (float)code;
    if (tid < 32)
      ((float4*)(out_zq + (size_t)token * DIM))[tid] =
          ((const float4*)(cb + (size_t)code * DIM))[tid];
  }
}

// -------------------------------------------------------------------------
extern "C" void kernel_launch(void* const* d_in, const int* in_sizes, int n_in,
                              void* d_out, int out_size, void* d_ws,
                              size_t ws_size, hipStream_t stream) {
  const float* ze = (const float*)d_in[0];
  const float* cb = (const float*)d_in[1];
  float* out = (float*)d_out;

  unsigned short* Cs = (unsigned short*)d_ws;
  float* cnorm = (float*)((char*)d_ws + CNORM_OFF);
  int* qcnt = (int*)((char*)d_ws + QCNT_OFF);
  int* qtok = (int*)((char*)d_ws + QTOK_OFF);
  unsigned long long* kmin = (unsigned long long*)((char*)d_ws + KMIN_OFF);

  prep_kernel<<<KCODES / 4, 256, 0, stream>>>(cb, Cs, cnorm, qcnt);
  vq_mfma_kernel<<<M_TOK / BM, 256, 0, stream>>>(
      ze, Cs, cnorm, cb, qcnt, qtok, kmin, out, out + (size_t)M_TOK * DIM);
  rescan_part_kernel<<<4096, 256, 0, stream>>>(ze, cb, cnorm, qcnt, qtok,
                                               kmin);
  rescan_apply_kernel<<<256, 256, 0, stream>>>(cb, qcnt, qtok, kmin, out,
                                               out + (size_t)M_TOK * DIM);
}